// Round 1
// baseline (959.016 us; speedup 1.0000x reference)
//
#include <hip/hip_runtime.h>

// ---------------------------------------------------------------------------
// GraphSAGE forward: 3x SAGEConv(mean) + ReLU(1,2) + final 128->2 projection
// fp32 everywhere. CSR built on-device each call (deterministic work).
// ---------------------------------------------------------------------------

constexpr int D_IN  = 128;
constexpr int D_HID = 256;
constexpr int D_EMB = 128;

// ---------------- CSR build ----------------

__global__ void count_deg_kernel(const int* __restrict__ dst, int* __restrict__ cnt, int E) {
    int stride = gridDim.x * blockDim.x;
    for (int i = blockIdx.x * blockDim.x + threadIdx.x; i < E; i += stride)
        atomicAdd(&cnt[dst[i]], 1);
}

__global__ __launch_bounds__(1024) void scan_kernel(const int* __restrict__ cnt,
                                                    int* __restrict__ row_ptr, int N) {
    __shared__ int wsum[16];
    __shared__ int carry_s;
    const int tid = threadIdx.x, lane = tid & 63, wid = tid >> 6;
    if (tid == 0) carry_s = 0;
    __syncthreads();
    for (int base = 0; base < N; base += 1024) {
        int i = base + tid;
        int v = (i < N) ? cnt[i] : 0;
        int xi = v;
        #pragma unroll
        for (int o = 1; o < 64; o <<= 1) {
            int t = __shfl_up(xi, o, 64);
            if (lane >= o) xi += t;
        }
        if (lane == 63) wsum[wid] = xi;
        __syncthreads();
        if (wid == 0) {
            int t = (lane < 16) ? wsum[lane] : 0;
            #pragma unroll
            for (int o = 1; o < 16; o <<= 1) {
                int u = __shfl_up(t, o, 64);
                if (lane >= o) t += u;
            }
            if (lane < 16) wsum[lane] = t;
        }
        __syncthreads();
        int waveoff = wid ? wsum[wid - 1] : 0;
        int total = wsum[15];
        if (i < N) row_ptr[i] = carry_s + waveoff + xi - v;  // exclusive
        __syncthreads();
        if (tid == 0) carry_s += total;
        __syncthreads();
    }
    if (tid == 0) row_ptr[N] = carry_s;
}

__global__ void scatter_kernel(const int* __restrict__ src, const int* __restrict__ dst,
                               const int* __restrict__ row_ptr, int* __restrict__ cursor,
                               int* __restrict__ esrc, int E) {
    int stride = gridDim.x * blockDim.x;
    for (int i = blockIdx.x * blockDim.x + threadIdx.x; i < E; i += stride) {
        int d = dst[i];
        int p = atomicAdd(&cursor[d], 1);
        esrc[row_ptr[d] + p] = src[i];
    }
}

// ---------------- mean aggregation (one wave per node) ----------------

template <int D>
__global__ __launch_bounds__(256) void aggregate_mean_kernel(
    const float* __restrict__ x, const int* __restrict__ row_ptr,
    const int* __restrict__ esrc, float* __restrict__ agg, int Nn) {
    constexpr int VEC = D / 64;
    const int lane = threadIdx.x & 63;
    const int wave = (blockIdx.x * blockDim.x + threadIdx.x) >> 6;
    const int nw = (gridDim.x * blockDim.x) >> 6;
    for (int node = wave; node < Nn; node += nw) {
        int beg = row_ptr[node], end = row_ptr[node + 1];
        float acc[VEC] = {};
        for (int e = beg; e < end; ++e) {
            int s = esrc[e];
            const float* p = x + (size_t)s * D + lane * VEC;
            if constexpr (VEC == 2) {
                float2 v = *(const float2*)p;
                acc[0] += v.x; acc[1] += v.y;
            } else {
                float4 v = *(const float4*)p;
                acc[0] += v.x; acc[1] += v.y; acc[2] += v.z; acc[3] += v.w;
            }
        }
        float inv = 1.0f / fmaxf((float)(end - beg), 1.0f);
        float* o = agg + (size_t)node * D + lane * VEC;
        if constexpr (VEC == 2) {
            *(float2*)o = make_float2(acc[0] * inv, acc[1] * inv);
        } else {
            float4 v;
            v.x = acc[0] * inv; v.y = acc[1] * inv; v.z = acc[2] * inv; v.w = acc[3] * inv;
            *(float4*)o = v;
        }
    }
}

// ---------------- fused GEMM: C = act(A1@W1 + A2@W2 + b) ----------------
// A1,A2: [M,K] row-major; W1,W2: [K,N] row-major; C: [M,N].

template <int K, int N, bool RELU>
__global__ __launch_bounds__(256) void fused_gemm_kernel(
    const float* __restrict__ A1, const float* __restrict__ A2,
    const float* __restrict__ W1, const float* __restrict__ W2,
    const float* __restrict__ bias, float* __restrict__ C, int M) {
    constexpr int BM = 64, BN = 64, BK = 32;
    __shared__ float sA1[BK][BM];
    __shared__ float sA2[BK][BM];
    __shared__ float sW1[BK][BN];
    __shared__ float sW2[BK][BN];
    const int tid = threadIdx.x;
    const int tr = tid & 15;   // row group (4 rows)
    const int tc = tid >> 4;   // col group (4 cols)
    const int bm = blockIdx.x * BM, bn = blockIdx.y * BN;
    float acc[4][4] = {};

    for (int k0 = 0; k0 < K; k0 += BK) {
        // stage A tiles, transposed to [BK][BM]
        #pragma unroll
        for (int t = tid; t < BM * BK / 4; t += 256) {
            int m = t >> 3;       // / (BK/4)
            int kq = t & 7;
            int row = bm + m;
            float4 v1, v2;
            if (row < M) {
                v1 = *(const float4*)(A1 + (size_t)row * K + k0 + kq * 4);
                v2 = *(const float4*)(A2 + (size_t)row * K + k0 + kq * 4);
            } else {
                v1 = make_float4(0.f, 0.f, 0.f, 0.f);
                v2 = v1;
            }
            sA1[kq * 4 + 0][m] = v1.x; sA1[kq * 4 + 1][m] = v1.y;
            sA1[kq * 4 + 2][m] = v1.z; sA1[kq * 4 + 3][m] = v1.w;
            sA2[kq * 4 + 0][m] = v2.x; sA2[kq * 4 + 1][m] = v2.y;
            sA2[kq * 4 + 2][m] = v2.z; sA2[kq * 4 + 3][m] = v2.w;
        }
        // stage W tiles [BK][BN]
        #pragma unroll
        for (int t = tid; t < BK * BN / 4; t += 256) {
            int kk = t >> 4;      // / (BN/4)
            int nq = t & 15;
            *(float4*)&sW1[kk][nq * 4] = *(const float4*)(W1 + (size_t)(k0 + kk) * N + bn + nq * 4);
            *(float4*)&sW2[kk][nq * 4] = *(const float4*)(W2 + (size_t)(k0 + kk) * N + bn + nq * 4);
        }
        __syncthreads();
        #pragma unroll
        for (int kk = 0; kk < BK; ++kk) {
            float4 a1 = *(const float4*)&sA1[kk][tr * 4];
            float4 a2 = *(const float4*)&sA2[kk][tr * 4];
            float4 w1 = *(const float4*)&sW1[kk][tc * 4];
            float4 w2 = *(const float4*)&sW2[kk][tc * 4];
            float a1v[4] = {a1.x, a1.y, a1.z, a1.w};
            float a2v[4] = {a2.x, a2.y, a2.z, a2.w};
            float w1v[4] = {w1.x, w1.y, w1.z, w1.w};
            float w2v[4] = {w2.x, w2.y, w2.z, w2.w};
            #pragma unroll
            for (int i2 = 0; i2 < 4; ++i2)
                #pragma unroll
                for (int j = 0; j < 4; ++j)
                    acc[i2][j] += a1v[i2] * w1v[j] + a2v[i2] * w2v[j];
        }
        __syncthreads();
    }

    #pragma unroll
    for (int i2 = 0; i2 < 4; ++i2) {
        int row = bm + tr * 4 + i2;
        if (row < M) {
            float4 o;
            o.x = acc[i2][0] + bias[bn + tc * 4 + 0];
            o.y = acc[i2][1] + bias[bn + tc * 4 + 1];
            o.z = acc[i2][2] + bias[bn + tc * 4 + 2];
            o.w = acc[i2][3] + bias[bn + tc * 4 + 3];
            if (RELU) {
                o.x = fmaxf(o.x, 0.f); o.y = fmaxf(o.y, 0.f);
                o.z = fmaxf(o.z, 0.f); o.w = fmaxf(o.w, 0.f);
            }
            *(float4*)(C + (size_t)row * N + bn + tc * 4) = o;
        }
    }
}

// ---------------- final projection: out = h @ Wout + bout  (128 -> 2) ----------------

__global__ __launch_bounds__(256) void out_proj_kernel(
    const float* __restrict__ h, const float* __restrict__ Wout,
    const float* __restrict__ bout, float* __restrict__ out, int Nn) {
    const int lane = threadIdx.x & 63;
    const int wave = (blockIdx.x * blockDim.x + threadIdx.x) >> 6;
    const int nw = (gridDim.x * blockDim.x) >> 6;
    float4 w = *(const float4*)(Wout + lane * 4);  // Wout[d][o]: w.x=W[2l][0] w.y=W[2l][1] w.z=W[2l+1][0] w.w=W[2l+1][1]
    float b0 = bout[0], b1 = bout[1];
    for (int node = wave; node < Nn; node += nw) {
        float2 v = *(const float2*)(h + (size_t)node * D_EMB + lane * 2);
        float p0 = v.x * w.x + v.y * w.z;
        float p1 = v.x * w.y + v.y * w.w;
        #pragma unroll
        for (int o = 32; o > 0; o >>= 1) {
            p0 += __shfl_down(p0, o, 64);
            p1 += __shfl_down(p1, o, 64);
        }
        if (lane == 0) *(float2*)(out + (size_t)node * 2) = make_float2(p0 + b0, p1 + b1);
    }
}

// ---------------- launch ----------------

extern "C" void kernel_launch(void* const* d_in, const int* in_sizes, int n_in,
                              void* d_out, int out_size, void* d_ws, size_t ws_size,
                              hipStream_t stream) {
    const float* x    = (const float*)d_in[0];
    const int*   ei   = (const int*)d_in[1];
    const float* Wl1  = (const float*)d_in[2];
    const float* Wr1  = (const float*)d_in[3];
    const float* b1   = (const float*)d_in[4];
    const float* Wl2  = (const float*)d_in[5];
    const float* Wr2  = (const float*)d_in[6];
    const float* b2   = (const float*)d_in[7];
    const float* Wl3  = (const float*)d_in[8];
    const float* Wr3  = (const float*)d_in[9];
    const float* b3   = (const float*)d_in[10];
    const float* Wout = (const float*)d_in[11];
    const float* bout = (const float*)d_in[12];

    const int Nn = in_sizes[0] / D_IN;     // 50000
    const int E  = in_sizes[1] / 2;        // 600000

    char* ws = (char*)d_ws;
    size_t off = 0;
    auto alloc = [&](size_t b) { size_t o = off; off = (off + b + 255) & ~(size_t)255; return o; };
    int*   row_ptr = (int*)(ws + alloc((size_t)(Nn + 1) * 4));
    int*   cnt     = (int*)(ws + alloc((size_t)Nn * 4));
    int*   cursor  = (int*)(ws + alloc((size_t)Nn * 4));
    int*   esrc    = (int*)(ws + alloc((size_t)E * 4));
    float* agg     = (float*)(ws + alloc((size_t)Nn * D_HID * 4));
    float* hA      = (float*)(ws + alloc((size_t)Nn * D_HID * 4));
    float* hB      = (float*)(ws + alloc((size_t)Nn * D_HID * 4));

    const int* src = ei;
    const int* dst = ei + E;

    hipMemsetAsync(cnt, 0, (size_t)Nn * 4, stream);
    hipMemsetAsync(cursor, 0, (size_t)Nn * 4, stream);

    count_deg_kernel<<<2048, 256, 0, stream>>>(dst, cnt, E);
    scan_kernel<<<1, 1024, 0, stream>>>(cnt, row_ptr, Nn);
    scatter_kernel<<<2048, 256, 0, stream>>>(src, dst, row_ptr, cursor, esrc, E);

    const int gm = (Nn + 63) / 64;

    // Layer 1: 128 -> 256, relu
    aggregate_mean_kernel<128><<<2048, 256, 0, stream>>>(x, row_ptr, esrc, agg, Nn);
    fused_gemm_kernel<128, 256, true><<<dim3(gm, 4), 256, 0, stream>>>(agg, x, Wl1, Wr1, b1, hA, Nn);

    // Layer 2: 256 -> 256, relu
    aggregate_mean_kernel<256><<<2048, 256, 0, stream>>>(hA, row_ptr, esrc, agg, Nn);
    fused_gemm_kernel<256, 256, true><<<dim3(gm, 4), 256, 0, stream>>>(agg, hA, Wl2, Wr2, b2, hB, Nn);

    // Layer 3: 256 -> 128, no relu
    aggregate_mean_kernel<256><<<2048, 256, 0, stream>>>(hB, row_ptr, esrc, agg, Nn);
    fused_gemm_kernel<256, 128, false><<<dim3(gm, 2), 256, 0, stream>>>(agg, hB, Wl3, Wr3, b3, hA, Nn);

    // Output projection
    out_proj_kernel<<<1024, 256, 0, stream>>>(hA, Wout, bout, (float*)d_out, Nn);
}

// Round 2
// 580.970 us; speedup vs baseline: 1.6507x; 1.6507x over previous
//
#include <hip/hip_runtime.h>

// ---------------------------------------------------------------------------
// GraphSAGE forward: 3x SAGEConv(mean) + ReLU(1,2) + final 128->2 projection.
// GEMMs via split-bf16 (hi/lo) 3-term MFMA: A@W ~= Ah@Wh + Ah@Wl + Al@Wh.
// Fused SAGE GEMM: [agg | x] @ [Wl ; Wr] (K concatenated).
// ---------------------------------------------------------------------------

constexpr int D_IN  = 128;
constexpr int D_HID = 256;
constexpr int D_EMB = 128;

typedef __attribute__((ext_vector_type(8))) short short8x;
typedef __attribute__((ext_vector_type(4))) float f32x4;

// ---------------- CSR build ----------------

__global__ void count_deg_kernel(const int* __restrict__ dst, int* __restrict__ cnt, int E) {
    int stride = gridDim.x * blockDim.x;
    for (int i = blockIdx.x * blockDim.x + threadIdx.x; i < E; i += stride)
        atomicAdd(&cnt[dst[i]], 1);
}

__global__ __launch_bounds__(1024) void scan_kernel(const int* __restrict__ cnt,
                                                    int* __restrict__ row_ptr, int N) {
    __shared__ int wsum[16];
    __shared__ int carry_s;
    const int tid = threadIdx.x, lane = tid & 63, wid = tid >> 6;
    if (tid == 0) carry_s = 0;
    __syncthreads();
    for (int base = 0; base < N; base += 1024) {
        int i = base + tid;
        int v = (i < N) ? cnt[i] : 0;
        int xi = v;
        #pragma unroll
        for (int o = 1; o < 64; o <<= 1) {
            int t = __shfl_up(xi, o, 64);
            if (lane >= o) xi += t;
        }
        if (lane == 63) wsum[wid] = xi;
        __syncthreads();
        if (wid == 0) {
            int t = (lane < 16) ? wsum[lane] : 0;
            #pragma unroll
            for (int o = 1; o < 16; o <<= 1) {
                int u = __shfl_up(t, o, 64);
                if (lane >= o) t += u;
            }
            if (lane < 16) wsum[lane] = t;
        }
        __syncthreads();
        int waveoff = wid ? wsum[wid - 1] : 0;
        int total = wsum[15];
        if (i < N) row_ptr[i] = carry_s + waveoff + xi - v;  // exclusive
        __syncthreads();
        if (tid == 0) carry_s += total;
        __syncthreads();
    }
    if (tid == 0) row_ptr[N] = carry_s;
}

__global__ void scatter_kernel(const int* __restrict__ src, const int* __restrict__ dst,
                               const int* __restrict__ row_ptr, int* __restrict__ cursor,
                               int* __restrict__ esrc, int E) {
    int stride = gridDim.x * blockDim.x;
    for (int i = blockIdx.x * blockDim.x + threadIdx.x; i < E; i += stride) {
        int d = dst[i];
        int p = atomicAdd(&cursor[d], 1);
        esrc[row_ptr[d] + p] = src[i];
    }
}

// ---------------- weight prep: W_cat^T split to bf16 hi/lo, [N][K1+K2] ----------------

__global__ void prep_wt_kernel(const float* __restrict__ Wl, const float* __restrict__ Wr,
                               int K1, int K2, int Nc,
                               short* __restrict__ WTh, short* __restrict__ WTl) {
    const int KE = K1 + K2;
    const int total = Nc * KE;
    int i = blockIdx.x * blockDim.x + threadIdx.x;
    if (i >= total) return;
    int n = i / KE, k = i - n * KE;
    float w = (k < K1) ? Wl[(size_t)k * Nc + n] : Wr[(size_t)(k - K1) * Nc + n];
    unsigned u = __float_as_uint(w);
    unsigned rb = (u + 0x7fffu + ((u >> 16) & 1u)) >> 16;   // RNE hi
    float hf = __uint_as_float(rb << 16);
    float r = w - hf;
    unsigned ul = __float_as_uint(r);
    unsigned rl = (ul + 0x7fffu + ((ul >> 16) & 1u)) >> 16; // RNE lo
    WTh[i] = (short)rb;
    WTl[i] = (short)rl;
}

// ---------------- mean aggregation (one wave per node) ----------------

template <int D>
__global__ __launch_bounds__(256) void aggregate_mean_kernel(
    const float* __restrict__ x, const int* __restrict__ row_ptr,
    const int* __restrict__ esrc, float* __restrict__ agg, int Nn) {
    constexpr int VEC = D / 64;
    const int lane = threadIdx.x & 63;
    const int wave = (blockIdx.x * blockDim.x + threadIdx.x) >> 6;
    const int nw = (gridDim.x * blockDim.x) >> 6;
    for (int node = wave; node < Nn; node += nw) {
        int beg = row_ptr[node], end = row_ptr[node + 1];
        float acc[VEC] = {};
        for (int e = beg; e < end; ++e) {
            int s = esrc[e];
            const float* p = x + (size_t)s * D + lane * VEC;
            if constexpr (VEC == 2) {
                float2 v = *(const float2*)p;
                acc[0] += v.x; acc[1] += v.y;
            } else {
                float4 v = *(const float4*)p;
                acc[0] += v.x; acc[1] += v.y; acc[2] += v.z; acc[3] += v.w;
            }
        }
        float inv = 1.0f / fmaxf((float)(end - beg), 1.0f);
        float* o = agg + (size_t)node * D + lane * VEC;
        if constexpr (VEC == 2) {
            *(float2*)o = make_float2(acc[0] * inv, acc[1] * inv);
        } else {
            float4 v;
            v.x = acc[0] * inv; v.y = acc[1] * inv; v.z = acc[2] * inv; v.w = acc[3] * inv;
            *(float4*)o = v;
        }
    }
}

// ---------------- split helpers ----------------

__device__ inline void split8(float4 a, float4 b, short8x& hi, short8x& lo) {
    float f[8] = {a.x, a.y, a.z, a.w, b.x, b.y, b.z, b.w};
    #pragma unroll
    for (int i = 0; i < 8; ++i) {
        unsigned u = __float_as_uint(f[i]);
        unsigned hb = u & 0xFFFF0000u;      // truncated hi (lo absorbs the error)
        hi[i] = (short)(u >> 16);
        float r = f[i] - __uint_as_float(hb);
        lo[i] = (short)(__float_as_uint(r) >> 16);
    }
}

// ---------------- split-bf16 MFMA GEMM: C = act([A1|A2] @ Wcat + b) ----------------
// A1:[M][K1], A2:[M][K2] fp32 row-major. WTh/WTl: [N][K1+K2] bf16 (pre-transposed).
// Tile BM x BN, BK=32, 256 threads = 4 waves, each wave 64x64 (4x4 16x16 frags).

template <int K1, int K2, int N, int BM, int BN, bool RELU>
__global__ __launch_bounds__(256) void gemm_split_kernel(
    const float* __restrict__ A1, const float* __restrict__ A2,
    const short* __restrict__ WTh, const short* __restrict__ WTl,
    const float* __restrict__ bias, float* __restrict__ C, int M) {
    constexpr int KEFF = K1 + K2;
    constexpr int BK = 32;
    constexpr int WN = BN / 64;           // waves along n  (BM/64 * WN == 4)
    __shared__ short sAh[BM][BK];
    __shared__ short sAl[BM][BK];
    __shared__ short sWh[BN][BK];
    __shared__ short sWl[BN][BK];
    const int tid = threadIdx.x;
    const int lane = tid & 63, wid = tid >> 6;
    const int wr = wid / WN, wc = wid % WN;
    const int bm = blockIdx.x * BM, bn = blockIdx.y * BN;

    f32x4 acc[4][4];
    #pragma unroll
    for (int m = 0; m < 4; ++m)
        #pragma unroll
        for (int n = 0; n < 4; ++n)
            acc[m][n] = (f32x4){0.f, 0.f, 0.f, 0.f};

    for (int k0 = 0; k0 < KEFF; k0 += BK) {
        const float* Asrc; int kloc, astr;
        if (k0 < K1) { Asrc = A1; kloc = k0;      astr = K1; }
        else         { Asrc = A2; kloc = k0 - K1; astr = K2; }

        // ---- stage A (fp32 -> hi/lo bf16, XOR-swizzled LDS) ----
        if constexpr (BM == 64) {
            const int ar = tid >> 2, sl = tid & 3;
            const int grow = bm + ar;
            float4 v0{}, v1{};
            if (grow < M) {
                const float* p = Asrc + (size_t)grow * astr + kloc + sl * 8;
                v0 = *(const float4*)p;
                v1 = *(const float4*)(p + 4);
            }
            short8x hi, lo;
            split8(v0, v1, hi, lo);
            const int ps = (sl ^ ((ar >> 1) & 3)) * 8;
            *(short8x*)&sAh[ar][ps] = hi;
            *(short8x*)&sAl[ar][ps] = lo;
        } else {  // BM == 128
            const int ar = tid >> 1, c0 = (tid & 1) * 16;
            const int grow = bm + ar;
            float4 v0{}, v1{}, v2{}, v3{};
            if (grow < M) {
                const float* p = Asrc + (size_t)grow * astr + kloc + c0;
                v0 = *(const float4*)p;       v1 = *(const float4*)(p + 4);
                v2 = *(const float4*)(p + 8); v3 = *(const float4*)(p + 12);
            }
            short8x h0, l0, h1, l1;
            split8(v0, v1, h0, l0);
            split8(v2, v3, h1, l1);
            const int f = (ar >> 1) & 3;
            const int s0 = ((c0 >> 3) ^ f) * 8, s1 = (((c0 >> 3) + 1) ^ f) * 8;
            *(short8x*)&sAh[ar][s0] = h0;
            *(short8x*)&sAh[ar][s1] = h1;
            *(short8x*)&sAl[ar][s0] = l0;
            *(short8x*)&sAl[ar][s1] = l1;
        }

        // ---- stage W (bf16 direct, swizzled) ----
        if constexpr (BN == 256) {
            const int nr = tid;
            const short* ph = WTh + (size_t)(bn + nr) * KEFF + k0;
            const short* pl = WTl + (size_t)(bn + nr) * KEFF + k0;
            const int f = (nr >> 1) & 3;
            #pragma unroll
            for (int s = 0; s < 4; ++s) {
                *(short8x*)&sWh[nr][(s ^ f) * 8] = *(const short8x*)(ph + s * 8);
                *(short8x*)&sWl[nr][(s ^ f) * 8] = *(const short8x*)(pl + s * 8);
            }
        } else {  // BN == 128
            const int nr = tid >> 1, sb = (tid & 1) * 2;
            const short* ph = WTh + (size_t)(bn + nr) * KEFF + k0;
            const short* pl = WTl + (size_t)(bn + nr) * KEFF + k0;
            const int f = (nr >> 1) & 3;
            #pragma unroll
            for (int s = 0; s < 2; ++s) {
                *(short8x*)&sWh[nr][((sb + s) ^ f) * 8] = *(const short8x*)(ph + (sb + s) * 8);
                *(short8x*)&sWl[nr][((sb + s) ^ f) * 8] = *(const short8x*)(pl + (sb + s) * 8);
            }
        }
        __syncthreads();

        // ---- fragments + MFMA ----
        short8x ah[4], al[4], bh[4], bl[4];
        #pragma unroll
        for (int m = 0; m < 4; ++m) {
            int row = wr * 64 + m * 16 + (lane & 15);
            int ps = (((lane >> 4) ^ ((row >> 1) & 3))) * 8;
            ah[m] = *(short8x*)&sAh[row][ps];
            al[m] = *(short8x*)&sAl[row][ps];
        }
        #pragma unroll
        for (int n = 0; n < 4; ++n) {
            int row = wc * 64 + n * 16 + (lane & 15);
            int ps = (((lane >> 4) ^ ((row >> 1) & 3))) * 8;
            bh[n] = *(short8x*)&sWh[row][ps];
            bl[n] = *(short8x*)&sWl[row][ps];
        }
        #pragma unroll
        for (int m = 0; m < 4; ++m)
            #pragma unroll
            for (int n = 0; n < 4; ++n) {
                acc[m][n] = __builtin_amdgcn_mfma_f32_16x16x32_bf16(ah[m], bh[n], acc[m][n], 0, 0, 0);
                acc[m][n] = __builtin_amdgcn_mfma_f32_16x16x32_bf16(ah[m], bl[n], acc[m][n], 0, 0, 0);
                acc[m][n] = __builtin_amdgcn_mfma_f32_16x16x32_bf16(al[m], bh[n], acc[m][n], 0, 0, 0);
            }
        __syncthreads();
    }

    // ---- epilogue: bias + relu, fp32 store ----
    #pragma unroll
    for (int n = 0; n < 4; ++n) {
        const int col = bn + wc * 64 + n * 16 + (lane & 15);
        const float bv = bias[col];
        #pragma unroll
        for (int m = 0; m < 4; ++m) {
            #pragma unroll
            for (int j = 0; j < 4; ++j) {
                int row = bm + wr * 64 + m * 16 + (lane >> 4) * 4 + j;
                if (row < M) {
                    float v = acc[m][n][j] + bv;
                    if (RELU) v = fmaxf(v, 0.f);
                    C[(size_t)row * N + col] = v;
                }
            }
        }
    }
}

// ---------------- final projection: out = h @ Wout + bout  (128 -> 2) ----------------

__global__ __launch_bounds__(256) void out_proj_kernel(
    const float* __restrict__ h, const float* __restrict__ Wout,
    const float* __restrict__ bout, float* __restrict__ out, int Nn) {
    const int lane = threadIdx.x & 63;
    const int wave = (blockIdx.x * blockDim.x + threadIdx.x) >> 6;
    const int nw = (gridDim.x * blockDim.x) >> 6;
    float4 w = *(const float4*)(Wout + lane * 4);  // W[2l][0], W[2l][1], W[2l+1][0], W[2l+1][1]
    float b0 = bout[0], b1 = bout[1];
    for (int node = wave; node < Nn; node += nw) {
        float2 v = *(const float2*)(h + (size_t)node * D_EMB + lane * 2);
        float p0 = v.x * w.x + v.y * w.z;
        float p1 = v.x * w.y + v.y * w.w;
        #pragma unroll
        for (int o = 32; o > 0; o >>= 1) {
            p0 += __shfl_down(p0, o, 64);
            p1 += __shfl_down(p1, o, 64);
        }
        if (lane == 0) *(float2*)(out + (size_t)node * 2) = make_float2(p0 + b0, p1 + b1);
    }
}

// ---------------- launch ----------------

extern "C" void kernel_launch(void* const* d_in, const int* in_sizes, int n_in,
                              void* d_out, int out_size, void* d_ws, size_t ws_size,
                              hipStream_t stream) {
    const float* x    = (const float*)d_in[0];
    const int*   ei   = (const int*)d_in[1];
    const float* Wl1  = (const float*)d_in[2];
    const float* Wr1  = (const float*)d_in[3];
    const float* b1   = (const float*)d_in[4];
    const float* Wl2  = (const float*)d_in[5];
    const float* Wr2  = (const float*)d_in[6];
    const float* b2   = (const float*)d_in[7];
    const float* Wl3  = (const float*)d_in[8];
    const float* Wr3  = (const float*)d_in[9];
    const float* b3   = (const float*)d_in[10];
    const float* Wout = (const float*)d_in[11];
    const float* bout = (const float*)d_in[12];

    const int Nn = in_sizes[0] / D_IN;     // 50000
    const int E  = in_sizes[1] / 2;        // 600000

    char* ws = (char*)d_ws;
    size_t off = 0;
    auto alloc = [&](size_t b) { size_t o = off; off = (off + b + 255) & ~(size_t)255; return o; };
    int*   row_ptr = (int*)(ws + alloc((size_t)(Nn + 1) * 4));
    int*   cnt     = (int*)(ws + alloc((size_t)Nn * 4));
    int*   cursor  = (int*)(ws + alloc((size_t)Nn * 4));
    int*   esrc    = (int*)(ws + alloc((size_t)E * 4));
    float* agg     = (float*)(ws + alloc((size_t)Nn * D_HID * 4));
    float* hA      = (float*)(ws + alloc((size_t)Nn * D_HID * 4));
    float* hB      = (float*)(ws + alloc((size_t)Nn * D_HID * 4));
    short* wt1h    = (short*)(ws + alloc((size_t)256 * 256 * 2));
    short* wt1l    = (short*)(ws + alloc((size_t)256 * 256 * 2));
    short* wt2h    = (short*)(ws + alloc((size_t)256 * 512 * 2));
    short* wt2l    = (short*)(ws + alloc((size_t)256 * 512 * 2));
    short* wt3h    = (short*)(ws + alloc((size_t)128 * 512 * 2));
    short* wt3l    = (short*)(ws + alloc((size_t)128 * 512 * 2));

    const int* src = ei;
    const int* dst = ei + E;

    hipMemsetAsync(cnt, 0, (size_t)Nn * 4, stream);
    hipMemsetAsync(cursor, 0, (size_t)Nn * 4, stream);

    count_deg_kernel<<<2048, 256, 0, stream>>>(dst, cnt, E);
    scan_kernel<<<1, 1024, 0, stream>>>(cnt, row_ptr, Nn);
    scatter_kernel<<<2048, 256, 0, stream>>>(src, dst, row_ptr, cursor, esrc, E);

    prep_wt_kernel<<<(256 * 256 + 255) / 256, 256, 0, stream>>>(Wl1, Wr1, 128, 128, 256, wt1h, wt1l);
    prep_wt_kernel<<<(256 * 512 + 255) / 256, 256, 0, stream>>>(Wl2, Wr2, 256, 256, 256, wt2h, wt2l);
    prep_wt_kernel<<<(128 * 512 + 255) / 256, 256, 0, stream>>>(Wl3, Wr3, 256, 256, 128, wt3h, wt3l);

    const int gm64  = (Nn + 63) / 64;    // 782
    const int gm128 = (Nn + 127) / 128;  // 391

    // Layer 1: [agg128 | x128] -> 256, relu
    aggregate_mean_kernel<128><<<2048, 256, 0, stream>>>(x, row_ptr, esrc, agg, Nn);
    gemm_split_kernel<128, 128, 256, 64, 256, true>
        <<<dim3(gm64, 1), 256, 0, stream>>>(agg, x, wt1h, wt1l, b1, hA, Nn);

    // Layer 2: [agg256 | h1] -> 256, relu
    aggregate_mean_kernel<256><<<2048, 256, 0, stream>>>(hA, row_ptr, esrc, agg, Nn);
    gemm_split_kernel<256, 256, 256, 64, 256, true>
        <<<dim3(gm64, 1), 256, 0, stream>>>(agg, hA, wt2h, wt2l, b2, hB, Nn);

    // Layer 3: [agg256 | h2] -> 128, no relu
    aggregate_mean_kernel<256><<<2048, 256, 0, stream>>>(hB, row_ptr, esrc, agg, Nn);
    gemm_split_kernel<256, 256, 128, 128, 128, false>
        <<<dim3(gm128, 1), 256, 0, stream>>>(agg, hB, wt3h, wt3l, b3, hA, Nn);

    // Output projection
    out_proj_kernel<<<1024, 256, 0, stream>>>(hA, Wout, bout, (float*)d_out, Nn);
}

// Round 3
// 465.330 us; speedup vs baseline: 2.0609x; 1.2485x over previous
//
#include <hip/hip_runtime.h>

// ---------------------------------------------------------------------------
// GraphSAGE forward: 3x SAGEConv(mean) + ReLU(1,2) + final 128->2 projection.
// GEMMs: split-bf16 (hi/lo) 3-term MFMA, W pre-swizzled to fragment layout in
// global (direct B loads, L2-hot), A double-buffered in LDS via
// global_load_lds with source-side XOR swizzle. One barrier per K-step.
// ---------------------------------------------------------------------------

constexpr int D_IN  = 128;
constexpr int D_HID = 256;
constexpr int D_EMB = 128;

typedef __attribute__((ext_vector_type(8))) short short8x;
typedef __attribute__((ext_vector_type(4))) float f32x4;

// ---------------- CSR build ----------------

__global__ void count_deg_kernel(const int* __restrict__ dst, int* __restrict__ cnt, int E) {
    int stride = gridDim.x * blockDim.x;
    for (int i = blockIdx.x * blockDim.x + threadIdx.x; i < E; i += stride)
        atomicAdd(&cnt[dst[i]], 1);
}

// hierarchical scan over Nn+1 elements (cnt[i] for i<Nn, 0 at i=Nn)
__global__ __launch_bounds__(1024) void scan_local_kernel(
    const int* __restrict__ cnt, int* __restrict__ row_ptr,
    int* __restrict__ bsums, int Nn) {
    __shared__ int wsum[16];
    const int tid = threadIdx.x, lane = tid & 63, wid = tid >> 6;
    const int idx0 = blockIdx.x * 4096 + tid * 4;
    int v[4];
    #pragma unroll
    for (int j = 0; j < 4; ++j) {
        int idx = idx0 + j;
        v[j] = (idx < Nn) ? cnt[idx] : 0;
    }
    int s = v[0] + v[1] + v[2] + v[3];
    int xi = s;
    #pragma unroll
    for (int o = 1; o < 64; o <<= 1) {
        int t = __shfl_up(xi, o, 64);
        if (lane >= o) xi += t;
    }
    if (lane == 63) wsum[wid] = xi;
    __syncthreads();
    if (wid == 0) {
        int t = (lane < 16) ? wsum[lane] : 0;
        #pragma unroll
        for (int o = 1; o < 16; o <<= 1) {
            int u = __shfl_up(t, o, 64);
            if (lane >= o) t += u;
        }
        if (lane < 16) wsum[lane] = t;
    }
    __syncthreads();
    int off = (wid ? wsum[wid - 1] : 0) + xi - s;
    int run = off;
    #pragma unroll
    for (int j = 0; j < 4; ++j) {
        int idx = idx0 + j;
        if (idx <= Nn) row_ptr[idx] = run;
        run += v[j];
    }
    if (tid == 0) bsums[blockIdx.x] = wsum[15];
}

__global__ void scan_bsums_kernel(int* __restrict__ bsums, int nb) {
    int lane = threadIdx.x & 63;
    int v = (lane < nb) ? bsums[lane] : 0;
    int xi = v;
    #pragma unroll
    for (int o = 1; o < 64; o <<= 1) {
        int t = __shfl_up(xi, o, 64);
        if (lane >= o) xi += t;
    }
    if (lane < nb) bsums[lane] = xi - v;  // exclusive
}

__global__ __launch_bounds__(1024) void scan_add_kernel(
    int* __restrict__ row_ptr, const int* __restrict__ bsums, int Nn) {
    const int b = blockIdx.x;
    const int base = bsums[b];
    const int idx0 = b * 4096 + threadIdx.x * 4;
    #pragma unroll
    for (int j = 0; j < 4; ++j) {
        int idx = idx0 + j;
        if (idx <= Nn) row_ptr[idx] += base;
    }
}

__global__ void scatter_kernel(const int* __restrict__ src, const int* __restrict__ dst,
                               const int* __restrict__ row_ptr, int* __restrict__ cursor,
                               int* __restrict__ esrc, int E) {
    int stride = gridDim.x * blockDim.x;
    for (int i = blockIdx.x * blockDim.x + threadIdx.x; i < E; i += stride) {
        int d = dst[i];
        int p = atomicAdd(&cursor[d], 1);
        esrc[row_ptr[d] + p] = src[i];
    }
}

// ---------------- weight prep: fragment-linear hi/lo bf16 ----------------
// Layout: WTh[(((n16*KSTEPS + k32)*64 + lane)*8 + e], where
// n = n16*16 + (lane&15), k = k32*32 + (lane>>4)*8 + e.

__global__ void prep_wt_kernel(const float* __restrict__ Wl, const float* __restrict__ Wr,
                               int K1, int K2, int Nc,
                               short* __restrict__ WTh, short* __restrict__ WTl) {
    const int KE = K1 + K2;
    const int KSTEPS = KE / 32;
    const int total = Nc * KE;
    int i = blockIdx.x * blockDim.x + threadIdx.x;
    if (i >= total) return;
    int e = i & 7;
    int t = i >> 3;
    int l = t & 63;
    int t2 = t >> 6;
    int k32 = t2 % KSTEPS;
    int n16 = t2 / KSTEPS;
    int n = n16 * 16 + (l & 15);
    int k = k32 * 32 + (l >> 4) * 8 + e;
    float w = (k < K1) ? Wl[(size_t)k * Nc + n] : Wr[(size_t)(k - K1) * Nc + n];
    unsigned u = __float_as_uint(w);
    unsigned rb = (u + 0x7fffu + ((u >> 16) & 1u)) >> 16;   // RNE hi
    float hf = __uint_as_float(rb << 16);
    float r = w - hf;
    unsigned ul = __float_as_uint(r);
    unsigned rl = (ul + 0x7fffu + ((ul >> 16) & 1u)) >> 16; // RNE lo
    WTh[i] = (short)rb;
    WTl[i] = (short)rl;
}

// ---------------- mean aggregation (one wave per node, 2-edge unroll) ------

template <int D>
__global__ __launch_bounds__(256) void aggregate_mean_kernel(
    const float* __restrict__ x, const int* __restrict__ row_ptr,
    const int* __restrict__ esrc, float* __restrict__ agg, int Nn) {
    constexpr int VEC = D / 64;
    const int lane = threadIdx.x & 63;
    const int wave = (blockIdx.x * blockDim.x + threadIdx.x) >> 6;
    const int nw = (gridDim.x * blockDim.x) >> 6;
    for (int node = wave; node < Nn; node += nw) {
        int beg = row_ptr[node], end = row_ptr[node + 1];
        float a0[VEC] = {}, a1[VEC] = {};
        int e = beg;
        for (; e + 2 <= end; e += 2) {
            int s0 = esrc[e], s1 = esrc[e + 1];
            const float* p0 = x + (size_t)s0 * D + lane * VEC;
            const float* p1 = x + (size_t)s1 * D + lane * VEC;
            if constexpr (VEC == 2) {
                float2 u0 = *(const float2*)p0;
                float2 u1 = *(const float2*)p1;
                a0[0] += u0.x; a0[1] += u0.y;
                a1[0] += u1.x; a1[1] += u1.y;
            } else {
                float4 u0 = *(const float4*)p0;
                float4 u1 = *(const float4*)p1;
                a0[0] += u0.x; a0[1] += u0.y; a0[2] += u0.z; a0[3] += u0.w;
                a1[0] += u1.x; a1[1] += u1.y; a1[2] += u1.z; a1[3] += u1.w;
            }
        }
        if (e < end) {
            int s0 = esrc[e];
            const float* p0 = x + (size_t)s0 * D + lane * VEC;
            if constexpr (VEC == 2) {
                float2 u0 = *(const float2*)p0;
                a0[0] += u0.x; a0[1] += u0.y;
            } else {
                float4 u0 = *(const float4*)p0;
                a0[0] += u0.x; a0[1] += u0.y; a0[2] += u0.z; a0[3] += u0.w;
            }
        }
        float inv = 1.0f / fmaxf((float)(end - beg), 1.0f);
        float* o = agg + (size_t)node * D + lane * VEC;
        if constexpr (VEC == 2) {
            *(float2*)o = make_float2((a0[0] + a1[0]) * inv, (a0[1] + a1[1]) * inv);
        } else {
            float4 v;
            v.x = (a0[0] + a1[0]) * inv; v.y = (a0[1] + a1[1]) * inv;
            v.z = (a0[2] + a1[2]) * inv; v.w = (a0[3] + a1[3]) * inv;
            *(float4*)o = v;
        }
    }
}

// ---------------- split helper ----------------

__device__ inline void split8(float4 a, float4 b, short8x& hi, short8x& lo) {
    float f[8] = {a.x, a.y, a.z, a.w, b.x, b.y, b.z, b.w};
    #pragma unroll
    for (int i = 0; i < 8; ++i) {
        unsigned u = __float_as_uint(f[i]);
        unsigned hb = u & 0xFFFF0000u;      // truncated hi (lo absorbs the error)
        hi[i] = (short)(u >> 16);
        float r = f[i] - __uint_as_float(hb);
        lo[i] = (short)(__float_as_uint(r) >> 16);
    }
}

// ---------------- split-bf16 MFMA GEMM ----------------
// C = act([A1|A2] @ Wcat + b).  A1:[M][K1], A2:[M][K2] fp32 row-major.
// WTh/WTl: fragment-linear (see prep). 256 thr = 4 waves, wave grid WR x WN,
// BM = WR*64, BN = WN*64 = N (single block-column, bn = 0).
// A: fp32 in LDS, double-buffered via global_load_lds, src-side XOR swizzle.

template <int K1, int K2, int N, int WR, int WN, bool RELU>
__global__ __launch_bounds__(256) void gemm_mfma_kernel(
    const float* __restrict__ A1, const float* __restrict__ A2,
    const short8x* __restrict__ WTh, const short8x* __restrict__ WTl,
    const float* __restrict__ bias, float* __restrict__ C, int M) {
    constexpr int KEFF = K1 + K2;
    constexpr int KSTEPS = KEFF / 32;
    constexpr int BM = WR * 64;
    __shared__ __attribute__((aligned(16))) float sA[2][BM][32];
    const int tid = threadIdx.x, lane = tid & 63, wid = tid >> 6;
    const int wr = wid / WN, wc = wid % WN;
    const int bm = blockIdx.x * BM;

    // stage one BK=32 tile of A (fp32) into sA[buf] with src-side swizzle:
    // LDS is linear [row][16B-slot]; slot s holds logical 32B-granule (s>>1)^(row&3).
    auto stage = [&](int buf, int ks) {
        int k0 = ks * 32;
        const float* Ab; int kloc, Kx;
        if (k0 < K1) { Ab = A1; kloc = k0;      Kx = K1; }
        else         { Ab = A2; kloc = k0 - K1; Kx = K2; }
        #pragma unroll
        for (int j = 0; j < BM / 32; ++j) {
            int r0 = wid * (BM / 4) + j * 8;       // wave-uniform
            int r = r0 + (lane >> 3);
            int grow = bm + r; if (grow >= M) grow = M - 1;
            int sl = lane & 7;
            int srcoff = ((((sl >> 1) ^ (r & 3)) << 5) | ((sl & 1) << 4));
            const char* g = (const char*)(Ab + (size_t)grow * Kx + kloc) + srcoff;
            __builtin_amdgcn_global_load_lds((const unsigned*)g,
                                             (unsigned*)&sA[buf][r0][0], 16, 0, 0);
        }
    };

    f32x4 acc[4][4];
    #pragma unroll
    for (int m = 0; m < 4; ++m)
        #pragma unroll
        for (int n = 0; n < 4; ++n)
            acc[m][n] = (f32x4){0.f, 0.f, 0.f, 0.f};

    stage(0, 0);
    __syncthreads();

    for (int ks = 0; ks < KSTEPS; ++ks) {
        const int cur = ks & 1;
        if (ks + 1 < KSTEPS) stage(cur ^ 1, ks + 1);   // prefetch next tile

        // B fragments direct from global (L2-hot, fragment-linear layout)
        short8x bh[4], bl[4];
        #pragma unroll
        for (int n = 0; n < 4; ++n) {
            size_t widx = ((size_t)(wc * 4 + n) * KSTEPS + ks) * 64 + lane;
            bh[n] = WTh[widx];
            bl[n] = WTl[widx];
        }

        // A fragments from LDS (swizzled read) + in-register hi/lo split
        short8x ah[4], al[4];
        const int gl = lane >> 4;
        #pragma unroll
        for (int m = 0; m < 4; ++m) {
            int rr = wr * 64 + m * 16 + (lane & 15);
            int g = gl ^ (rr & 3);
            const float4* pa = (const float4*)&sA[cur][rr][g * 8];
            float4 v0 = pa[0], v1 = pa[1];
            split8(v0, v1, ah[m], al[m]);
        }

        #pragma unroll
        for (int m = 0; m < 4; ++m)
            #pragma unroll
            for (int n = 0; n < 4; ++n) {
                acc[m][n] = __builtin_amdgcn_mfma_f32_16x16x32_bf16(ah[m], bh[n], acc[m][n], 0, 0, 0);
                acc[m][n] = __builtin_amdgcn_mfma_f32_16x16x32_bf16(ah[m], bl[n], acc[m][n], 0, 0, 0);
                acc[m][n] = __builtin_amdgcn_mfma_f32_16x16x32_bf16(al[m], bh[n], acc[m][n], 0, 0, 0);
            }
        __syncthreads();   // drains vmcnt (prefetch done) + lgkm (reads done)
    }

    // epilogue: bias + relu, fp32 store
    #pragma unroll
    for (int n = 0; n < 4; ++n) {
        const int col = wc * 64 + n * 16 + (lane & 15);
        const float bv = bias[col];
        #pragma unroll
        for (int m = 0; m < 4; ++m) {
            #pragma unroll
            for (int j = 0; j < 4; ++j) {
                int row = bm + wr * 64 + m * 16 + (lane >> 4) * 4 + j;
                if (row < M) {
                    float v = acc[m][n][j] + bv;
                    if (RELU) v = fmaxf(v, 0.f);
                    C[(size_t)row * N + col] = v;
                }
            }
        }
    }
}

// ---------------- final projection: out = h @ Wout + bout  (128 -> 2) ------

__global__ __launch_bounds__(256) void out_proj_kernel(
    const float* __restrict__ h, const float* __restrict__ Wout,
    const float* __restrict__ bout, float* __restrict__ out, int Nn) {
    const int lane = threadIdx.x & 63;
    const int wave = (blockIdx.x * blockDim.x + threadIdx.x) >> 6;
    const int nw = (gridDim.x * blockDim.x) >> 6;
    float4 w = *(const float4*)(Wout + lane * 4);
    float b0 = bout[0], b1 = bout[1];
    for (int node = wave; node < Nn; node += nw) {
        float2 v = *(const float2*)(h + (size_t)node * D_EMB + lane * 2);
        float p0 = v.x * w.x + v.y * w.z;
        float p1 = v.x * w.y + v.y * w.w;
        #pragma unroll
        for (int o = 32; o > 0; o >>= 1) {
            p0 += __shfl_down(p0, o, 64);
            p1 += __shfl_down(p1, o, 64);
        }
        if (lane == 0) *(float2*)(out + (size_t)node * 2) = make_float2(p0 + b0, p1 + b1);
    }
}

// ---------------- launch ----------------

extern "C" void kernel_launch(void* const* d_in, const int* in_sizes, int n_in,
                              void* d_out, int out_size, void* d_ws, size_t ws_size,
                              hipStream_t stream) {
    const float* x    = (const float*)d_in[0];
    const int*   ei   = (const int*)d_in[1];
    const float* Wl1  = (const float*)d_in[2];
    const float* Wr1  = (const float*)d_in[3];
    const float* b1   = (const float*)d_in[4];
    const float* Wl2  = (const float*)d_in[5];
    const float* Wr2  = (const float*)d_in[6];
    const float* b2   = (const float*)d_in[7];
    const float* Wl3  = (const float*)d_in[8];
    const float* Wr3  = (const float*)d_in[9];
    const float* b3   = (const float*)d_in[10];
    const float* Wout = (const float*)d_in[11];
    const float* bout = (const float*)d_in[12];

    const int Nn = in_sizes[0] / D_IN;     // 50000
    const int E  = in_sizes[1] / 2;        // 600000

    char* ws = (char*)d_ws;
    size_t off = 0;
    auto alloc = [&](size_t b) { size_t o = off; off = (off + b + 255) & ~(size_t)255; return o; };
    int*   row_ptr = (int*)(ws + alloc((size_t)(Nn + 1) * 4));
    int*   cnt     = (int*)(ws + alloc((size_t)Nn * 4));
    int*   cursor  = (int*)(ws + alloc((size_t)Nn * 4));
    int*   bsums   = (int*)(ws + alloc((size_t)256 * 4));
    int*   esrc    = (int*)(ws + alloc((size_t)E * 4));
    float* agg     = (float*)(ws + alloc((size_t)Nn * D_HID * 4));
    float* hA      = (float*)(ws + alloc((size_t)Nn * D_HID * 4));
    float* hB      = (float*)(ws + alloc((size_t)Nn * D_HID * 4));
    short* wt1h    = (short*)(ws + alloc((size_t)256 * 256 * 2));
    short* wt1l    = (short*)(ws + alloc((size_t)256 * 256 * 2));
    short* wt2h    = (short*)(ws + alloc((size_t)256 * 512 * 2));
    short* wt2l    = (short*)(ws + alloc((size_t)256 * 512 * 2));
    short* wt3h    = (short*)(ws + alloc((size_t)128 * 512 * 2));
    short* wt3l    = (short*)(ws + alloc((size_t)128 * 512 * 2));

    const int* src = ei;
    const int* dst = ei + E;

    hipMemsetAsync(cnt, 0, (size_t)Nn * 4, stream);
    hipMemsetAsync(cursor, 0, (size_t)Nn * 4, stream);

    prep_wt_kernel<<<(256 * 256 + 255) / 256, 256, 0, stream>>>(Wl1, Wr1, 128, 128, 256, wt1h, wt1l);
    prep_wt_kernel<<<(256 * 512 + 255) / 256, 256, 0, stream>>>(Wl2, Wr2, 256, 256, 256, wt2h, wt2l);
    prep_wt_kernel<<<(128 * 512 + 255) / 256, 256, 0, stream>>>(Wl3, Wr3, 256, 256, 128, wt3h, wt3l);

    count_deg_kernel<<<2048, 256, 0, stream>>>(dst, cnt, E);
    const int nb = (Nn + 1 + 4095) / 4096;   // 13
    scan_local_kernel<<<nb, 1024, 0, stream>>>(cnt, row_ptr, bsums, Nn);
    scan_bsums_kernel<<<1, 64, 0, stream>>>(bsums, nb);
    scan_add_kernel<<<nb, 1024, 0, stream>>>(row_ptr, bsums, Nn);
    scatter_kernel<<<2048, 256, 0, stream>>>(src, dst, row_ptr, cursor, esrc, E);

    const int gm64  = (Nn + 63) / 64;    // 782
    const int gm128 = (Nn + 127) / 128;  // 391

    // Layer 1: [agg128 | x128] -> 256, relu
    aggregate_mean_kernel<128><<<2048, 256, 0, stream>>>(x, row_ptr, esrc, agg, Nn);
    gemm_mfma_kernel<128, 128, 256, 1, 4, true>
        <<<gm64, 256, 0, stream>>>(agg, x, (const short8x*)wt1h, (const short8x*)wt1l, b1, hA, Nn);

    // Layer 2: [agg256 | h1] -> 256, relu
    aggregate_mean_kernel<256><<<2048, 256, 0, stream>>>(hA, row_ptr, esrc, agg, Nn);
    gemm_mfma_kernel<256, 256, 256, 1, 4, true>
        <<<gm64, 256, 0, stream>>>(agg, hA, (const short8x*)wt2h, (const short8x*)wt2l, b2, hB, Nn);

    // Layer 3: [agg256 | h2] -> 128, no relu
    aggregate_mean_kernel<256><<<2048, 256, 0, stream>>>(hB, row_ptr, esrc, agg, Nn);
    gemm_mfma_kernel<256, 256, 128, 2, 2, false>
        <<<gm128, 256, 0, stream>>>(agg, hB, (const short8x*)wt3h, (const short8x*)wt3l, b3, hA, Nn);

    // Output projection
    out_proj_kernel<<<1024, 256, 0, stream>>>(hA, Wout, bout, (float*)d_out, Nn);
}

// Round 4
// 374.419 us; speedup vs baseline: 2.5613x; 1.2428x over previous
//
#include <hip/hip_runtime.h>

// ---------------------------------------------------------------------------
// GraphSAGE forward: 3x SAGEConv(mean) + ReLU(1,2) + final 128->2 projection.
// Layers 1-2: split-bf16 (hi/lo) 3-term MFMA GEMM, W pre-swizzled to fragment
// layout (direct B loads), A double-buffered in LDS via global_load_lds.
// Layer 3 + out-proj collapsed algebraically:
//   out_i = mean_j(h2_j @ Wl3@Wout) + h2_i @ Wr3@Wout + (b3@Wout + bout)
// -> tiny [256][4] fused weight, D=2 gather instead of D=256.
// ---------------------------------------------------------------------------

constexpr int D_IN  = 128;
constexpr int D_HID = 256;

typedef __attribute__((ext_vector_type(8))) short short8x;
typedef __attribute__((ext_vector_type(4))) float f32x4;

// ---------------- CSR build ----------------

__global__ void count_deg_kernel(const int* __restrict__ dst, int* __restrict__ cnt, int E) {
    int stride = gridDim.x * blockDim.x;
    for (int i = blockIdx.x * blockDim.x + threadIdx.x; i < E; i += stride)
        atomicAdd(&cnt[dst[i]], 1);
}

__global__ __launch_bounds__(1024) void scan_local_kernel(
    const int* __restrict__ cnt, int* __restrict__ row_ptr,
    int* __restrict__ bsums, int Nn) {
    __shared__ int wsum[16];
    const int tid = threadIdx.x, lane = tid & 63, wid = tid >> 6;
    const int idx0 = blockIdx.x * 4096 + tid * 4;
    int v[4];
    #pragma unroll
    for (int j = 0; j < 4; ++j) {
        int idx = idx0 + j;
        v[j] = (idx < Nn) ? cnt[idx] : 0;
    }
    int s = v[0] + v[1] + v[2] + v[3];
    int xi = s;
    #pragma unroll
    for (int o = 1; o < 64; o <<= 1) {
        int t = __shfl_up(xi, o, 64);
        if (lane >= o) xi += t;
    }
    if (lane == 63) wsum[wid] = xi;
    __syncthreads();
    if (wid == 0) {
        int t = (lane < 16) ? wsum[lane] : 0;
        #pragma unroll
        for (int o = 1; o < 16; o <<= 1) {
            int u = __shfl_up(t, o, 64);
            if (lane >= o) t += u;
        }
        if (lane < 16) wsum[lane] = t;
    }
    __syncthreads();
    int off = (wid ? wsum[wid - 1] : 0) + xi - s;
    int run = off;
    #pragma unroll
    for (int j = 0; j < 4; ++j) {
        int idx = idx0 + j;
        if (idx <= Nn) row_ptr[idx] = run;
        run += v[j];
    }
    if (tid == 0) bsums[blockIdx.x] = wsum[15];
}

__global__ void scan_bsums_kernel(int* __restrict__ bsums, int nb) {
    int lane = threadIdx.x & 63;
    int v = (lane < nb) ? bsums[lane] : 0;
    int xi = v;
    #pragma unroll
    for (int o = 1; o < 64; o <<= 1) {
        int t = __shfl_up(xi, o, 64);
        if (lane >= o) xi += t;
    }
    if (lane < nb) bsums[lane] = xi - v;  // exclusive
}

__global__ __launch_bounds__(1024) void scan_add_kernel(
    int* __restrict__ row_ptr, const int* __restrict__ bsums, int Nn) {
    const int b = blockIdx.x;
    const int base = bsums[b];
    const int idx0 = b * 4096 + threadIdx.x * 4;
    #pragma unroll
    for (int j = 0; j < 4; ++j) {
        int idx = idx0 + j;
        if (idx <= Nn) row_ptr[idx] += base;
    }
}

__global__ void scatter_kernel(const int* __restrict__ src, const int* __restrict__ dst,
                               const int* __restrict__ row_ptr, int* __restrict__ cursor,
                               int* __restrict__ esrc, int E) {
    int stride = gridDim.x * blockDim.x;
    for (int i = blockIdx.x * blockDim.x + threadIdx.x; i < E; i += stride) {
        int d = dst[i];
        int p = atomicAdd(&cursor[d], 1);
        esrc[row_ptr[d] + p] = src[i];
    }
}

// ---------------- weight prep: fragment-linear hi/lo bf16 ----------------

__global__ void prep_wt_kernel(const float* __restrict__ Wl, const float* __restrict__ Wr,
                               int K1, int K2, int Nc,
                               short* __restrict__ WTh, short* __restrict__ WTl) {
    const int KE = K1 + K2;
    const int KSTEPS = KE / 32;
    const int total = Nc * KE;
    int i = blockIdx.x * blockDim.x + threadIdx.x;
    if (i >= total) return;
    int e = i & 7;
    int t = i >> 3;
    int l = t & 63;
    int t2 = t >> 6;
    int k32 = t2 % KSTEPS;
    int n16 = t2 / KSTEPS;
    int n = n16 * 16 + (l & 15);
    int k = k32 * 32 + (l >> 4) * 8 + e;
    float w = (k < K1) ? Wl[(size_t)k * Nc + n] : Wr[(size_t)(k - K1) * Nc + n];
    unsigned u = __float_as_uint(w);
    unsigned rb = (u + 0x7fffu + ((u >> 16) & 1u)) >> 16;   // RNE hi
    float hf = __uint_as_float(rb << 16);
    float r = w - hf;
    unsigned ul = __float_as_uint(r);
    unsigned rl = (ul + 0x7fffu + ((ul >> 16) & 1u)) >> 16; // RNE lo
    WTh[i] = (short)rb;
    WTl[i] = (short)rl;
}

// ---------------- fused layer3+out weights: Wc[256][4], bc[2] ----------------
// Wc[h][0..1] = (Wl3 @ Wout)[h][0..1]; Wc[h][2..3] = (Wr3 @ Wout)[h][0..1]
// bc[o] = (b3 @ Wout)[o] + bout[o]

__global__ __launch_bounds__(1024) void prep_wc_kernel(
    const float* __restrict__ Wl3, const float* __restrict__ Wr3,
    const float* __restrict__ b3, const float* __restrict__ Wout,
    const float* __restrict__ bout, float* __restrict__ Wc, float* __restrict__ bc) {
    int tid = threadIdx.x;         // 1024 threads: h = tid>>2 in [0,256), c = tid&3
    int h = tid >> 2, c = tid & 3;
    const float* Ws = (c < 2) ? Wl3 : Wr3;
    int o = c & 1;
    float s = 0.f;
    for (int e = 0; e < 128; ++e) s += Ws[h * 128 + e] * Wout[e * 2 + o];
    Wc[h * 4 + c] = s;
    if (tid < 2) {
        float sb = 0.f;
        for (int e = 0; e < 128; ++e) sb += b3[e] * Wout[e * 2 + tid];
        bc[tid] = sb + bout[tid];
    }
}

// ---------------- mean aggregation (one wave per node, 4-edge unroll) ------

template <int D>
__global__ __launch_bounds__(256) void aggregate_mean_kernel(
    const float* __restrict__ x, const int* __restrict__ row_ptr,
    const int* __restrict__ esrc, float* __restrict__ agg, int Nn) {
    constexpr int VEC = D / 64;
    const int lane = threadIdx.x & 63;
    const int wave = (blockIdx.x * blockDim.x + threadIdx.x) >> 6;
    const int nw = (gridDim.x * blockDim.x) >> 6;
    for (int node = wave; node < Nn; node += nw) {
        int beg = row_ptr[node], end = row_ptr[node + 1];
        float acc[4][VEC] = {};
        int e = beg;
        for (; e + 4 <= end; e += 4) {
            int s0 = esrc[e], s1 = esrc[e + 1], s2 = esrc[e + 2], s3 = esrc[e + 3];
            const float* p0 = x + (size_t)s0 * D + lane * VEC;
            const float* p1 = x + (size_t)s1 * D + lane * VEC;
            const float* p2 = x + (size_t)s2 * D + lane * VEC;
            const float* p3 = x + (size_t)s3 * D + lane * VEC;
            if constexpr (VEC == 2) {
                float2 v0 = *(const float2*)p0, v1 = *(const float2*)p1;
                float2 v2 = *(const float2*)p2, v3 = *(const float2*)p3;
                acc[0][0] += v0.x; acc[0][1] += v0.y;
                acc[1][0] += v1.x; acc[1][1] += v1.y;
                acc[2][0] += v2.x; acc[2][1] += v2.y;
                acc[3][0] += v3.x; acc[3][1] += v3.y;
            } else {
                float4 v0 = *(const float4*)p0, v1 = *(const float4*)p1;
                float4 v2 = *(const float4*)p2, v3 = *(const float4*)p3;
                acc[0][0] += v0.x; acc[0][1] += v0.y; acc[0][2] += v0.z; acc[0][3] += v0.w;
                acc[1][0] += v1.x; acc[1][1] += v1.y; acc[1][2] += v1.z; acc[1][3] += v1.w;
                acc[2][0] += v2.x; acc[2][1] += v2.y; acc[2][2] += v2.z; acc[2][3] += v2.w;
                acc[3][0] += v3.x; acc[3][1] += v3.y; acc[3][2] += v3.z; acc[3][3] += v3.w;
            }
        }
        for (; e < end; ++e) {
            int s0 = esrc[e];
            const float* p0 = x + (size_t)s0 * D + lane * VEC;
            if constexpr (VEC == 2) {
                float2 v0 = *(const float2*)p0;
                acc[0][0] += v0.x; acc[0][1] += v0.y;
            } else {
                float4 v0 = *(const float4*)p0;
                acc[0][0] += v0.x; acc[0][1] += v0.y; acc[0][2] += v0.z; acc[0][3] += v0.w;
            }
        }
        float inv = 1.0f / fmaxf((float)(end - beg), 1.0f);
        float* o = agg + (size_t)node * D + lane * VEC;
        if constexpr (VEC == 2) {
            *(float2*)o = make_float2((acc[0][0] + acc[1][0] + acc[2][0] + acc[3][0]) * inv,
                                      (acc[0][1] + acc[1][1] + acc[2][1] + acc[3][1]) * inv);
        } else {
            float4 v;
            v.x = (acc[0][0] + acc[1][0] + acc[2][0] + acc[3][0]) * inv;
            v.y = (acc[0][1] + acc[1][1] + acc[2][1] + acc[3][1]) * inv;
            v.z = (acc[0][2] + acc[1][2] + acc[2][2] + acc[3][2]) * inv;
            v.w = (acc[0][3] + acc[1][3] + acc[2][3] + acc[3][3]) * inv;
            *(float4*)o = v;
        }
    }
}

// ---------------- split helper ----------------

__device__ inline void split8(float4 a, float4 b, short8x& hi, short8x& lo) {
    float f[8] = {a.x, a.y, a.z, a.w, b.x, b.y, b.z, b.w};
    #pragma unroll
    for (int i = 0; i < 8; ++i) {
        unsigned u = __float_as_uint(f[i]);
        unsigned hb = u & 0xFFFF0000u;      // truncated hi (lo absorbs the error)
        hi[i] = (short)(u >> 16);
        float r = f[i] - __uint_as_float(hb);
        lo[i] = (short)(__float_as_uint(r) >> 16);
    }
}

// ---------------- split-bf16 MFMA GEMM (layers 1-2) ----------------

template <int K1, int K2, int N, int WR, int WN, bool RELU>
__global__ __launch_bounds__(256) void gemm_mfma_kernel(
    const float* __restrict__ A1, const float* __restrict__ A2,
    const short8x* __restrict__ WTh, const short8x* __restrict__ WTl,
    const float* __restrict__ bias, float* __restrict__ C, int M) {
    constexpr int KEFF = K1 + K2;
    constexpr int KSTEPS = KEFF / 32;
    constexpr int BM = WR * 64;
    __shared__ __attribute__((aligned(16))) float sA[2][BM][32];
    const int tid = threadIdx.x, lane = tid & 63, wid = tid >> 6;
    const int wr = wid / WN, wc = wid % WN;
    const int bm = blockIdx.x * BM;

    auto stage = [&](int buf, int ks) {
        int k0 = ks * 32;
        const float* Ab; int kloc, Kx;
        if (k0 < K1) { Ab = A1; kloc = k0;      Kx = K1; }
        else         { Ab = A2; kloc = k0 - K1; Kx = K2; }
        #pragma unroll
        for (int j = 0; j < BM / 32; ++j) {
            int r0 = wid * (BM / 4) + j * 8;       // wave-uniform
            int r = r0 + (lane >> 3);
            int grow = bm + r; if (grow >= M) grow = M - 1;
            int sl = lane & 7;
            int srcoff = ((((sl >> 1) ^ (r & 3)) << 5) | ((sl & 1) << 4));
            const char* g = (const char*)(Ab + (size_t)grow * Kx + kloc) + srcoff;
            __builtin_amdgcn_global_load_lds((const unsigned*)g,
                                             (unsigned*)&sA[buf][r0][0], 16, 0, 0);
        }
    };

    f32x4 acc[4][4];
    #pragma unroll
    for (int m = 0; m < 4; ++m)
        #pragma unroll
        for (int n = 0; n < 4; ++n)
            acc[m][n] = (f32x4){0.f, 0.f, 0.f, 0.f};

    stage(0, 0);
    __syncthreads();

    for (int ks = 0; ks < KSTEPS; ++ks) {
        const int cur = ks & 1;
        if (ks + 1 < KSTEPS) stage(cur ^ 1, ks + 1);   // prefetch next tile

        short8x bh[4], bl[4];
        #pragma unroll
        for (int n = 0; n < 4; ++n) {
            size_t widx = ((size_t)(wc * 4 + n) * KSTEPS + ks) * 64 + lane;
            bh[n] = WTh[widx];
            bl[n] = WTl[widx];
        }

        short8x ah[4], al[4];
        const int gl = lane >> 4;
        #pragma unroll
        for (int m = 0; m < 4; ++m) {
            int rr = wr * 64 + m * 16 + (lane & 15);
            int g = gl ^ (rr & 3);
            const float4* pa = (const float4*)&sA[cur][rr][g * 8];
            float4 v0 = pa[0], v1 = pa[1];
            split8(v0, v1, ah[m], al[m]);
        }

        #pragma unroll
        for (int m = 0; m < 4; ++m)
            #pragma unroll
            for (int n = 0; n < 4; ++n) {
                acc[m][n] = __builtin_amdgcn_mfma_f32_16x16x32_bf16(ah[m], bh[n], acc[m][n], 0, 0, 0);
                acc[m][n] = __builtin_amdgcn_mfma_f32_16x16x32_bf16(ah[m], bl[n], acc[m][n], 0, 0, 0);
                acc[m][n] = __builtin_amdgcn_mfma_f32_16x16x32_bf16(al[m], bh[n], acc[m][n], 0, 0, 0);
            }
        __syncthreads();
    }

    #pragma unroll
    for (int n = 0; n < 4; ++n) {
        const int col = wc * 64 + n * 16 + (lane & 15);
        const float bv = bias[col];
        #pragma unroll
        for (int m = 0; m < 4; ++m) {
            #pragma unroll
            for (int j = 0; j < 4; ++j) {
                int row = bm + wr * 64 + m * 16 + (lane >> 4) * 4 + j;
                if (row < M) {
                    float v = acc[m][n][j] + bv;
                    if (RELU) v = fmaxf(v, 0.f);
                    C[(size_t)row * N + col] = v;
                }
            }
        }
    }
}

// ---------------- tu = h2 @ Wc (+bc on u-part): [Nn][4] -------------------
// 16 lanes per node (4 nodes/wave); butterfly reduce over 16 lanes.

__global__ __launch_bounds__(256) void tu_kernel(
    const float* __restrict__ h2, const float* __restrict__ Wc,
    const float* __restrict__ bc, float* __restrict__ tu, int Nn) {
    const int lane = threadIdx.x & 63;
    const int sub = lane >> 4;         // node within wave
    const int sl  = lane & 15;
    const int wave = (blockIdx.x * blockDim.x + threadIdx.x) >> 6;
    const int nw = (gridDim.x * blockDim.x) >> 6;
    const float bc0 = bc[0], bc1 = bc[1];
    for (int base = wave * 4; base < Nn; base += nw * 4) {
        int node = base + sub;
        float4 p = make_float4(0.f, 0.f, 0.f, 0.f);
        if (node < Nn) {
            const float* hp = h2 + (size_t)node * 256 + sl * 16;
            #pragma unroll
            for (int i = 0; i < 4; ++i) {
                float4 hv = *(const float4*)(hp + i * 4);
                const float* wp = Wc + (sl * 16 + i * 4) * 4;
                float4 w0 = *(const float4*)(wp);
                float4 w1 = *(const float4*)(wp + 4);
                float4 w2 = *(const float4*)(wp + 8);
                float4 w3 = *(const float4*)(wp + 12);
                p.x += hv.x * w0.x + hv.y * w1.x + hv.z * w2.x + hv.w * w3.x;
                p.y += hv.x * w0.y + hv.y * w1.y + hv.z * w2.y + hv.w * w3.y;
                p.z += hv.x * w0.z + hv.y * w1.z + hv.z * w2.z + hv.w * w3.z;
                p.w += hv.x * w0.w + hv.y * w1.w + hv.z * w2.w + hv.w * w3.w;
            }
        }
        #pragma unroll
        for (int m = 8; m >= 1; m >>= 1) {
            p.x += __shfl_xor(p.x, m, 64);
            p.y += __shfl_xor(p.y, m, 64);
            p.z += __shfl_xor(p.z, m, 64);
            p.w += __shfl_xor(p.w, m, 64);
        }
        if (sl == 0 && node < Nn) {
            p.z += bc0; p.w += bc1;
            *(float4*)(tu + (size_t)node * 4) = p;
        }
    }
}

// ---------------- out_i = mean_j t_j + u_i  (D=2 gather, L2-resident) ------

__global__ __launch_bounds__(256) void final_out_kernel(
    const float* __restrict__ tu, const int* __restrict__ row_ptr,
    const int* __restrict__ esrc, float* __restrict__ out, int Nn) {
    int stride = gridDim.x * blockDim.x;
    for (int i = blockIdx.x * blockDim.x + threadIdx.x; i < Nn; i += stride) {
        int beg = row_ptr[i], end = row_ptr[i + 1];
        float s0 = 0.f, s1 = 0.f;
        for (int e = beg; e < end; ++e) {
            int s = esrc[e];
            float2 tv = *(const float2*)(tu + (size_t)s * 4);
            s0 += tv.x; s1 += tv.y;
        }
        float inv = 1.0f / fmaxf((float)(end - beg), 1.0f);
        float u0 = tu[(size_t)i * 4 + 2], u1 = tu[(size_t)i * 4 + 3];
        *(float2*)(out + (size_t)i * 2) = make_float2(s0 * inv + u0, s1 * inv + u1);
    }
}

// ---------------- launch ----------------

extern "C" void kernel_launch(void* const* d_in, const int* in_sizes, int n_in,
                              void* d_out, int out_size, void* d_ws, size_t ws_size,
                              hipStream_t stream) {
    const float* x    = (const float*)d_in[0];
    const int*   ei   = (const int*)d_in[1];
    const float* Wl1  = (const float*)d_in[2];
    const float* Wr1  = (const float*)d_in[3];
    const float* b1   = (const float*)d_in[4];
    const float* Wl2  = (const float*)d_in[5];
    const float* Wr2  = (const float*)d_in[6];
    const float* b2   = (const float*)d_in[7];
    const float* Wl3  = (const float*)d_in[8];
    const float* Wr3  = (const float*)d_in[9];
    const float* b3   = (const float*)d_in[10];
    const float* Wout = (const float*)d_in[11];
    const float* bout = (const float*)d_in[12];

    const int Nn = in_sizes[0] / D_IN;     // 50000
    const int E  = in_sizes[1] / 2;        // 600000

    char* ws = (char*)d_ws;
    size_t off = 0;
    auto alloc = [&](size_t b) { size_t o = off; off = (off + b + 255) & ~(size_t)255; return o; };
    int*   row_ptr = (int*)(ws + alloc((size_t)(Nn + 1) * 4));
    int*   cnt     = (int*)(ws + alloc((size_t)Nn * 4));
    int*   cursor  = (int*)(ws + alloc((size_t)Nn * 4));
    int*   bsums   = (int*)(ws + alloc((size_t)256 * 4));
    int*   esrc    = (int*)(ws + alloc((size_t)E * 4));
    float* agg     = (float*)(ws + alloc((size_t)Nn * D_HID * 4));
    float* hA      = (float*)(ws + alloc((size_t)Nn * D_HID * 4));
    float* hB      = (float*)(ws + alloc((size_t)Nn * D_HID * 4));
    float* tu      = (float*)(ws + alloc((size_t)Nn * 4 * 4));
    float* Wc      = (float*)(ws + alloc((size_t)256 * 4 * 4));
    float* bc      = (float*)(ws + alloc((size_t)2 * 4));
    short* wt1h    = (short*)(ws + alloc((size_t)256 * 256 * 2));
    short* wt1l    = (short*)(ws + alloc((size_t)256 * 256 * 2));
    short* wt2h    = (short*)(ws + alloc((size_t)256 * 512 * 2));
    short* wt2l    = (short*)(ws + alloc((size_t)256 * 512 * 2));

    const int* src = ei;
    const int* dst = ei + E;

    hipMemsetAsync(cnt, 0, (size_t)Nn * 4, stream);
    hipMemsetAsync(cursor, 0, (size_t)Nn * 4, stream);

    prep_wt_kernel<<<(256 * 256 + 255) / 256, 256, 0, stream>>>(Wl1, Wr1, 128, 128, 256, wt1h, wt1l);
    prep_wt_kernel<<<(256 * 512 + 255) / 256, 256, 0, stream>>>(Wl2, Wr2, 256, 256, 256, wt2h, wt2l);
    prep_wc_kernel<<<1, 1024, 0, stream>>>(Wl3, Wr3, b3, Wout, bout, Wc, bc);

    count_deg_kernel<<<2048, 256, 0, stream>>>(dst, cnt, E);
    const int nb = (Nn + 1 + 4095) / 4096;   // 13
    scan_local_kernel<<<nb, 1024, 0, stream>>>(cnt, row_ptr, bsums, Nn);
    scan_bsums_kernel<<<1, 64, 0, stream>>>(bsums, nb);
    scan_add_kernel<<<nb, 1024, 0, stream>>>(row_ptr, bsums, Nn);
    scatter_kernel<<<2048, 256, 0, stream>>>(src, dst, row_ptr, cursor, esrc, E);

    const int gm64 = (Nn + 63) / 64;    // 782

    // Layer 1: [agg128 | x128] -> 256, relu
    aggregate_mean_kernel<128><<<2048, 256, 0, stream>>>(x, row_ptr, esrc, agg, Nn);
    gemm_mfma_kernel<128, 128, 256, 1, 4, true>
        <<<gm64, 256, 0, stream>>>(agg, x, (const short8x*)wt1h, (const short8x*)wt1l, b1, hA, Nn);

    // Layer 2: [agg256 | h1] -> 256, relu
    aggregate_mean_kernel<256><<<2048, 256, 0, stream>>>(hA, row_ptr, esrc, agg, Nn);
    gemm_mfma_kernel<256, 256, 256, 1, 4, true>
        <<<gm64, 256, 0, stream>>>(agg, hA, (const short8x*)wt2h, (const short8x*)wt2l, b2, hB, Nn);

    // Layer 3 + out-proj (collapsed): tu = h2 @ Wc, out = mean-gather(t) + u
    tu_kernel<<<2048, 256, 0, stream>>>(hB, Wc, bc, tu, Nn);
    final_out_kernel<<<512, 256, 0, stream>>>(tu, row_ptr, esrc, (float*)d_out, Nn);
}

// Round 5
// 327.911 us; speedup vs baseline: 2.9246x; 1.1418x over previous
//
#include <hip/hip_runtime.h>

// ---------------------------------------------------------------------------
// GraphSAGE forward: 3x SAGEConv(mean) + ReLU(1,2) + final 128->2 projection.
// Layers 1-2: split-bf16 (hi/lo) 3-term MFMA GEMM, W pre-swizzled to fragment
// layout (direct B loads), A double-buffered in LDS via global_load_lds.
// Neighbor gathers read bf16 copies (half the bytes); self-terms stay fp32.
// Layer 3 + out-proj collapsed algebraically to a [256][4] weight + D=2 gather.
// ---------------------------------------------------------------------------

constexpr int D_IN  = 128;
constexpr int D_HID = 256;

typedef __attribute__((ext_vector_type(8))) short short8x;
typedef __attribute__((ext_vector_type(4))) float f32x4;

// ---------------- CSR build ----------------

__global__ void count_deg_kernel(const int* __restrict__ dst, int* __restrict__ cnt, int E) {
    int stride = gridDim.x * blockDim.x;
    for (int i = blockIdx.x * blockDim.x + threadIdx.x; i < E; i += stride)
        atomicAdd(&cnt[dst[i]], 1);
}

__global__ __launch_bounds__(1024) void scan_local_kernel(
    const int* __restrict__ cnt, int* __restrict__ row_ptr,
    int* __restrict__ bsums, int Nn) {
    __shared__ int wsum[16];
    const int tid = threadIdx.x, lane = tid & 63, wid = tid >> 6;
    const int idx0 = blockIdx.x * 4096 + tid * 4;
    int v[4];
    #pragma unroll
    for (int j = 0; j < 4; ++j) {
        int idx = idx0 + j;
        v[j] = (idx < Nn) ? cnt[idx] : 0;
    }
    int s = v[0] + v[1] + v[2] + v[3];
    int xi = s;
    #pragma unroll
    for (int o = 1; o < 64; o <<= 1) {
        int t = __shfl_up(xi, o, 64);
        if (lane >= o) xi += t;
    }
    if (lane == 63) wsum[wid] = xi;
    __syncthreads();
    if (wid == 0) {
        int t = (lane < 16) ? wsum[lane] : 0;
        #pragma unroll
        for (int o = 1; o < 16; o <<= 1) {
            int u = __shfl_up(t, o, 64);
            if (lane >= o) t += u;
        }
        if (lane < 16) wsum[lane] = t;
    }
    __syncthreads();
    int off = (wid ? wsum[wid - 1] : 0) + xi - s;
    int run = off;
    #pragma unroll
    for (int j = 0; j < 4; ++j) {
        int idx = idx0 + j;
        if (idx <= Nn) row_ptr[idx] = run;
        run += v[j];
    }
    if (tid == 0) bsums[blockIdx.x] = wsum[15];
}

__global__ void scan_bsums_kernel(int* __restrict__ bsums, int nb) {
    int lane = threadIdx.x & 63;
    int v = (lane < nb) ? bsums[lane] : 0;
    int xi = v;
    #pragma unroll
    for (int o = 1; o < 64; o <<= 1) {
        int t = __shfl_up(xi, o, 64);
        if (lane >= o) xi += t;
    }
    if (lane < nb) bsums[lane] = xi - v;  // exclusive
}

__global__ __launch_bounds__(1024) void scan_add_kernel(
    int* __restrict__ row_ptr, const int* __restrict__ bsums, int Nn) {
    const int b = blockIdx.x;
    const int base = bsums[b];
    const int idx0 = b * 4096 + threadIdx.x * 4;
    #pragma unroll
    for (int j = 0; j < 4; ++j) {
        int idx = idx0 + j;
        if (idx <= Nn) row_ptr[idx] += base;
    }
}

__global__ void scatter_kernel(const int* __restrict__ src, const int* __restrict__ dst,
                               const int* __restrict__ row_ptr, int* __restrict__ cursor,
                               int* __restrict__ esrc, int E) {
    int stride = gridDim.x * blockDim.x;
    for (int i = blockIdx.x * blockDim.x + threadIdx.x; i < E; i += stride) {
        int d = dst[i];
        int p = atomicAdd(&cursor[d], 1);
        esrc[row_ptr[d] + p] = src[i];
    }
}

// ---------------- fp32 -> bf16 (RNE) convert ----------------

__global__ __launch_bounds__(256) void f32_to_bf16_kernel(
    const float* __restrict__ in, unsigned short* __restrict__ out, int n8) {
    int stride = gridDim.x * blockDim.x;
    for (int i = blockIdx.x * blockDim.x + threadIdx.x; i < n8; i += stride) {
        const float4* p = (const float4*)(in + (size_t)i * 8);
        float4 v0 = p[0], v1 = p[1];
        float f[8] = {v0.x, v0.y, v0.z, v0.w, v1.x, v1.y, v1.z, v1.w};
        unsigned r[8];
        #pragma unroll
        for (int j = 0; j < 8; ++j) {
            unsigned u = __float_as_uint(f[j]);
            r[j] = (u + 0x7fffu + ((u >> 16) & 1u)) >> 16;
        }
        uint4 o;
        o.x = r[0] | (r[1] << 16);
        o.y = r[2] | (r[3] << 16);
        o.z = r[4] | (r[5] << 16);
        o.w = r[6] | (r[7] << 16);
        *(uint4*)(out + (size_t)i * 8) = o;
    }
}

// ---------------- weight prep: fragment-linear hi/lo bf16 ----------------

__global__ void prep_wt_kernel(const float* __restrict__ Wl, const float* __restrict__ Wr,
                               int K1, int K2, int Nc,
                               short* __restrict__ WTh, short* __restrict__ WTl) {
    const int KE = K1 + K2;
    const int KSTEPS = KE / 32;
    const int total = Nc * KE;
    int i = blockIdx.x * blockDim.x + threadIdx.x;
    if (i >= total) return;
    int e = i & 7;
    int t = i >> 3;
    int l = t & 63;
    int t2 = t >> 6;
    int k32 = t2 % KSTEPS;
    int n16 = t2 / KSTEPS;
    int n = n16 * 16 + (l & 15);
    int k = k32 * 32 + (l >> 4) * 8 + e;
    float w = (k < K1) ? Wl[(size_t)k * Nc + n] : Wr[(size_t)(k - K1) * Nc + n];
    unsigned u = __float_as_uint(w);
    unsigned rb = (u + 0x7fffu + ((u >> 16) & 1u)) >> 16;   // RNE hi
    float hf = __uint_as_float(rb << 16);
    float r = w - hf;
    unsigned ul = __float_as_uint(r);
    unsigned rl = (ul + 0x7fffu + ((ul >> 16) & 1u)) >> 16; // RNE lo
    WTh[i] = (short)rb;
    WTl[i] = (short)rl;
}

// ---------------- fused layer3+out weights: Wc[256][4], bc[2] ----------------

__global__ __launch_bounds__(1024) void prep_wc_kernel(
    const float* __restrict__ Wl3, const float* __restrict__ Wr3,
    const float* __restrict__ b3, const float* __restrict__ Wout,
    const float* __restrict__ bout, float* __restrict__ Wc, float* __restrict__ bc) {
    int tid = threadIdx.x;         // h = tid>>2 in [0,256), c = tid&3
    int h = tid >> 2, c = tid & 3;
    const float* Ws = (c < 2) ? Wl3 : Wr3;
    int o = c & 1;
    float s = 0.f;
    for (int e = 0; e < 128; ++e) s += Ws[h * 128 + e] * Wout[e * 2 + o];
    Wc[h * 4 + c] = s;
    if (tid < 2) {
        float sb = 0.f;
        for (int e = 0; e < 128; ++e) sb += b3[e] * Wout[e * 2 + tid];
        bc[tid] = sb + bout[tid];
    }
}

// ---------------- mean aggregation over bf16 rows ----------------
// D bf16 per row; 16B (8 bf16) per lane; LPN = D/8 lanes per node,
// NPW = 64/LPN nodes per wave. fp32 accumulate, fp32 output.

__device__ inline void addbf8(const uint4& q, float* a) {
    a[0] += __uint_as_float(q.x << 16); a[1] += __uint_as_float(q.x & 0xFFFF0000u);
    a[2] += __uint_as_float(q.y << 16); a[3] += __uint_as_float(q.y & 0xFFFF0000u);
    a[4] += __uint_as_float(q.z << 16); a[5] += __uint_as_float(q.z & 0xFFFF0000u);
    a[6] += __uint_as_float(q.w << 16); a[7] += __uint_as_float(q.w & 0xFFFF0000u);
}

template <int D>
__global__ __launch_bounds__(256) void aggregate_bf16_kernel(
    const unsigned short* __restrict__ xb, const int* __restrict__ row_ptr,
    const int* __restrict__ esrc, float* __restrict__ agg, int Nn) {
    constexpr int LPN = D / 8;
    constexpr int NPW = 64 / LPN;
    const int lane = threadIdx.x & 63;
    const int sub = lane / LPN;
    const int sl = lane % LPN;
    const int wave = (blockIdx.x * blockDim.x + threadIdx.x) >> 6;
    const int nw = (gridDim.x * blockDim.x) >> 6;
    for (int base = wave * NPW; base < Nn; base += nw * NPW) {
        int node = base + sub;
        if (node >= Nn) continue;
        int beg = row_ptr[node], end = row_ptr[node + 1];
        float a0[8] = {}, a1[8] = {}, a2[8] = {}, a3[8] = {};
        int e = beg;
        for (; e + 4 <= end; e += 4) {
            int s0 = esrc[e], s1 = esrc[e + 1], s2 = esrc[e + 2], s3 = esrc[e + 3];
            uint4 q0 = *(const uint4*)(xb + (size_t)s0 * D + sl * 8);
            uint4 q1 = *(const uint4*)(xb + (size_t)s1 * D + sl * 8);
            uint4 q2 = *(const uint4*)(xb + (size_t)s2 * D + sl * 8);
            uint4 q3 = *(const uint4*)(xb + (size_t)s3 * D + sl * 8);
            addbf8(q0, a0); addbf8(q1, a1); addbf8(q2, a2); addbf8(q3, a3);
        }
        for (; e < end; ++e) {
            int s0 = esrc[e];
            uint4 q0 = *(const uint4*)(xb + (size_t)s0 * D + sl * 8);
            addbf8(q0, a0);
        }
        float inv = 1.0f / fmaxf((float)(end - beg), 1.0f);
        float r[8];
        #pragma unroll
        for (int i = 0; i < 8; ++i) r[i] = (a0[i] + a1[i] + a2[i] + a3[i]) * inv;
        float* o = agg + (size_t)node * D + sl * 8;
        *(float4*)o       = make_float4(r[0], r[1], r[2], r[3]);
        *(float4*)(o + 4) = make_float4(r[4], r[5], r[6], r[7]);
    }
}

// ---------------- split helper ----------------

__device__ inline void split8(float4 a, float4 b, short8x& hi, short8x& lo) {
    float f[8] = {a.x, a.y, a.z, a.w, b.x, b.y, b.z, b.w};
    #pragma unroll
    for (int i = 0; i < 8; ++i) {
        unsigned u = __float_as_uint(f[i]);
        unsigned hb = u & 0xFFFF0000u;      // truncated hi (lo absorbs the error)
        hi[i] = (short)(u >> 16);
        float r = f[i] - __uint_as_float(hb);
        lo[i] = (short)(__float_as_uint(r) >> 16);
    }
}

// ---------------- split-bf16 MFMA GEMM (layers 1-2) ----------------
// Optional dual-write: Cb = bf16(C) for the next layer's gather.

template <int K1, int K2, int N, int WR, int WN, bool RELU, bool WB16>
__global__ __launch_bounds__(256) void gemm_mfma_kernel(
    const float* __restrict__ A1, const float* __restrict__ A2,
    const short8x* __restrict__ WTh, const short8x* __restrict__ WTl,
    const float* __restrict__ bias, float* __restrict__ C,
    unsigned short* __restrict__ Cb, int M) {
    constexpr int KEFF = K1 + K2;
    constexpr int KSTEPS = KEFF / 32;
    constexpr int BM = WR * 64;
    __shared__ __attribute__((aligned(16))) float sA[2][BM][32];
    const int tid = threadIdx.x, lane = tid & 63, wid = tid >> 6;
    const int wr = wid / WN, wc = wid % WN;
    const int bm = blockIdx.x * BM;

    auto stage = [&](int buf, int ks) {
        int k0 = ks * 32;
        const float* Ab; int kloc, Kx;
        if (k0 < K1) { Ab = A1; kloc = k0;      Kx = K1; }
        else         { Ab = A2; kloc = k0 - K1; Kx = K2; }
        #pragma unroll
        for (int j = 0; j < BM / 32; ++j) {
            int r0 = wid * (BM / 4) + j * 8;       // wave-uniform
            int r = r0 + (lane >> 3);
            int grow = bm + r; if (grow >= M) grow = M - 1;
            int sl = lane & 7;
            int srcoff = ((((sl >> 1) ^ (r & 3)) << 5) | ((sl & 1) << 4));
            const char* g = (const char*)(Ab + (size_t)grow * Kx + kloc) + srcoff;
            __builtin_amdgcn_global_load_lds((const unsigned*)g,
                                             (unsigned*)&sA[buf][r0][0], 16, 0, 0);
        }
    };

    f32x4 acc[4][4];
    #pragma unroll
    for (int m = 0; m < 4; ++m)
        #pragma unroll
        for (int n = 0; n < 4; ++n)
            acc[m][n] = (f32x4){0.f, 0.f, 0.f, 0.f};

    stage(0, 0);
    __syncthreads();

    for (int ks = 0; ks < KSTEPS; ++ks) {
        const int cur = ks & 1;
        if (ks + 1 < KSTEPS) stage(cur ^ 1, ks + 1);   // prefetch next tile

        short8x bh[4], bl[4];
        #pragma unroll
        for (int n = 0; n < 4; ++n) {
            size_t widx = ((size_t)(wc * 4 + n) * KSTEPS + ks) * 64 + lane;
            bh[n] = WTh[widx];
            bl[n] = WTl[widx];
        }

        short8x ah[4], al[4];
        const int gl = lane >> 4;
        #pragma unroll
        for (int m = 0; m < 4; ++m) {
            int rr = wr * 64 + m * 16 + (lane & 15);
            int g = gl ^ (rr & 3);
            const float4* pa = (const float4*)&sA[cur][rr][g * 8];
            float4 v0 = pa[0], v1 = pa[1];
            split8(v0, v1, ah[m], al[m]);
        }

        #pragma unroll
        for (int m = 0; m < 4; ++m)
            #pragma unroll
            for (int n = 0; n < 4; ++n) {
                acc[m][n] = __builtin_amdgcn_mfma_f32_16x16x32_bf16(ah[m], bh[n], acc[m][n], 0, 0, 0);
                acc[m][n] = __builtin_amdgcn_mfma_f32_16x16x32_bf16(ah[m], bl[n], acc[m][n], 0, 0, 0);
                acc[m][n] = __builtin_amdgcn_mfma_f32_16x16x32_bf16(al[m], bh[n], acc[m][n], 0, 0, 0);
            }
        __syncthreads();
    }

    #pragma unroll
    for (int n = 0; n < 4; ++n) {
        const int col = wc * 64 + n * 16 + (lane & 15);
        const float bv = bias[col];
        #pragma unroll
        for (int m = 0; m < 4; ++m) {
            #pragma unroll
            for (int j = 0; j < 4; ++j) {
                int row = bm + wr * 64 + m * 16 + (lane >> 4) * 4 + j;
                if (row < M) {
                    float v = acc[m][n][j] + bv;
                    if (RELU) v = fmaxf(v, 0.f);
                    C[(size_t)row * N + col] = v;
                    if (WB16) {
                        unsigned u = __float_as_uint(v);
                        Cb[(size_t)row * N + col] =
                            (unsigned short)((u + 0x7fffu + ((u >> 16) & 1u)) >> 16);
                    }
                }
            }
        }
    }
}

// ---------------- tu = h2 @ Wc (+bc on u-part): [Nn][4] -------------------

__global__ __launch_bounds__(256) void tu_kernel(
    const float* __restrict__ h2, const float* __restrict__ Wc,
    const float* __restrict__ bc, float* __restrict__ tu, int Nn) {
    const int lane = threadIdx.x & 63;
    const int sub = lane >> 4;         // node within wave
    const int sl  = lane & 15;
    const int wave = (blockIdx.x * blockDim.x + threadIdx.x) >> 6;
    const int nw = (gridDim.x * blockDim.x) >> 6;
    const float bc0 = bc[0], bc1 = bc[1];
    for (int base = wave * 4; base < Nn; base += nw * 4) {
        int node = base + sub;
        float4 p = make_float4(0.f, 0.f, 0.f, 0.f);
        if (node < Nn) {
            const float* hp = h2 + (size_t)node * 256 + sl * 16;
            #pragma unroll
            for (int i = 0; i < 4; ++i) {
                float4 hv = *(const float4*)(hp + i * 4);
                const float* wp = Wc + (sl * 16 + i * 4) * 4;
                float4 w0 = *(const float4*)(wp);
                float4 w1 = *(const float4*)(wp + 4);
                float4 w2 = *(const float4*)(wp + 8);
                float4 w3 = *(const float4*)(wp + 12);
                p.x += hv.x * w0.x + hv.y * w1.x + hv.z * w2.x + hv.w * w3.x;
                p.y += hv.x * w0.y + hv.y * w1.y + hv.z * w2.y + hv.w * w3.y;
                p.z += hv.x * w0.z + hv.y * w1.z + hv.z * w2.z + hv.w * w3.z;
                p.w += hv.x * w0.w + hv.y * w1.w + hv.z * w2.w + hv.w * w3.w;
            }
        }
        #pragma unroll
        for (int m = 8; m >= 1; m >>= 1) {
            p.x += __shfl_xor(p.x, m, 64);
            p.y += __shfl_xor(p.y, m, 64);
            p.z += __shfl_xor(p.z, m, 64);
            p.w += __shfl_xor(p.w, m, 64);
        }
        if (sl == 0 && node < Nn) {
            p.z += bc0; p.w += bc1;
            *(float4*)(tu + (size_t)node * 4) = p;
        }
    }
}

// ---------------- out_i = mean_j t_j + u_i  (D=2 gather, L2-resident) ------

__global__ __launch_bounds__(256) void final_out_kernel(
    const float* __restrict__ tu, const int* __restrict__ row_ptr,
    const int* __restrict__ esrc, float* __restrict__ out, int Nn) {
    int stride = gridDim.x * blockDim.x;
    for (int i = blockIdx.x * blockDim.x + threadIdx.x; i < Nn; i += stride) {
        int beg = row_ptr[i], end = row_ptr[i + 1];
        float s0 = 0.f, s1 = 0.f;
        for (int e = beg; e < end; ++e) {
            int s = esrc[e];
            float2 tv = *(const float2*)(tu + (size_t)s * 4);
            s0 += tv.x; s1 += tv.y;
        }
        float inv = 1.0f / fmaxf((float)(end - beg), 1.0f);
        float u0 = tu[(size_t)i * 4 + 2], u1 = tu[(size_t)i * 4 + 3];
        *(float2*)(out + (size_t)i * 2) = make_float2(s0 * inv + u0, s1 * inv + u1);
    }
}

// ---------------- launch ----------------

extern "C" void kernel_launch(void* const* d_in, const int* in_sizes, int n_in,
                              void* d_out, int out_size, void* d_ws, size_t ws_size,
                              hipStream_t stream) {
    const float* x    = (const float*)d_in[0];
    const int*   ei   = (const int*)d_in[1];
    const float* Wl1  = (const float*)d_in[2];
    const float* Wr1  = (const float*)d_in[3];
    const float* b1   = (const float*)d_in[4];
    const float* Wl2  = (const float*)d_in[5];
    const float* Wr2  = (const float*)d_in[6];
    const float* b2   = (const float*)d_in[7];
    const float* Wl3  = (const float*)d_in[8];
    const float* Wr3  = (const float*)d_in[9];
    const float* b3   = (const float*)d_in[10];
    const float* Wout = (const float*)d_in[11];
    const float* bout = (const float*)d_in[12];

    const int Nn = in_sizes[0] / D_IN;     // 50000
    const int E  = in_sizes[1] / 2;        // 600000

    char* ws = (char*)d_ws;
    size_t off = 0;
    auto alloc = [&](size_t b) { size_t o = off; off = (off + b + 255) & ~(size_t)255; return o; };
    int*   row_ptr = (int*)(ws + alloc((size_t)(Nn + 1) * 4));
    int*   cnt     = (int*)(ws + alloc((size_t)Nn * 4));
    int*   cursor  = (int*)(ws + alloc((size_t)Nn * 4));
    int*   bsums   = (int*)(ws + alloc((size_t)256 * 4));
    int*   esrc    = (int*)(ws + alloc((size_t)E * 4));
    float* agg     = (float*)(ws + alloc((size_t)Nn * D_HID * 4));
    float* hA      = (float*)(ws + alloc((size_t)Nn * D_HID * 4));
    float* hB      = (float*)(ws + alloc((size_t)Nn * D_HID * 4));
    float* tu      = (float*)(ws + alloc((size_t)Nn * 4 * 4));
    float* Wc      = (float*)(ws + alloc((size_t)256 * 4 * 4));
    float* bc      = (float*)(ws + alloc((size_t)2 * 4));
    unsigned short* xb  = (unsigned short*)(ws + alloc((size_t)Nn * D_IN * 2));
    unsigned short* hAb = (unsigned short*)(ws + alloc((size_t)Nn * D_HID * 2));
    short* wt1h    = (short*)(ws + alloc((size_t)256 * 256 * 2));
    short* wt1l    = (short*)(ws + alloc((size_t)256 * 256 * 2));
    short* wt2h    = (short*)(ws + alloc((size_t)256 * 512 * 2));
    short* wt2l    = (short*)(ws + alloc((size_t)256 * 512 * 2));

    const int* src = ei;
    const int* dst = ei + E;

    hipMemsetAsync(cnt, 0, (size_t)Nn * 4, stream);
    hipMemsetAsync(cursor, 0, (size_t)Nn * 4, stream);

    prep_wt_kernel<<<(256 * 256 + 255) / 256, 256, 0, stream>>>(Wl1, Wr1, 128, 128, 256, wt1h, wt1l);
    prep_wt_kernel<<<(256 * 512 + 255) / 256, 256, 0, stream>>>(Wl2, Wr2, 256, 256, 256, wt2h, wt2l);
    prep_wc_kernel<<<1, 1024, 0, stream>>>(Wl3, Wr3, b3, Wout, bout, Wc, bc);
    f32_to_bf16_kernel<<<2048, 256, 0, stream>>>(x, xb, Nn * D_IN / 8);

    count_deg_kernel<<<2048, 256, 0, stream>>>(dst, cnt, E);
    const int nb = (Nn + 1 + 4095) / 4096;   // 13
    scan_local_kernel<<<nb, 1024, 0, stream>>>(cnt, row_ptr, bsums, Nn);
    scan_bsums_kernel<<<1, 64, 0, stream>>>(bsums, nb);
    scan_add_kernel<<<nb, 1024, 0, stream>>>(row_ptr, bsums, Nn);
    scatter_kernel<<<2048, 256, 0, stream>>>(src, dst, row_ptr, cursor, esrc, E);

    const int gm64 = (Nn + 63) / 64;    // 782

    // Layer 1: [agg128 | x128] -> 256, relu; dual-write hA fp32 + hAb bf16
    aggregate_bf16_kernel<128><<<2048, 256, 0, stream>>>(xb, row_ptr, esrc, agg, Nn);
    gemm_mfma_kernel<128, 128, 256, 1, 4, true, true>
        <<<gm64, 256, 0, stream>>>(agg, x, (const short8x*)wt1h, (const short8x*)wt1l, b1, hA, hAb, Nn);

    // Layer 2: [agg256 | h1] -> 256, relu
    aggregate_bf16_kernel<256><<<2048, 256, 0, stream>>>(hAb, row_ptr, esrc, agg, Nn);
    gemm_mfma_kernel<256, 256, 256, 1, 4, true, false>
        <<<gm64, 256, 0, stream>>>(agg, hA, (const short8x*)wt2h, (const short8x*)wt2l, b2, hB, nullptr, Nn);

    // Layer 3 + out-proj (collapsed): tu = h2 @ Wc, out = mean-gather(t) + u
    tu_kernel<<<2048, 256, 0, stream>>>(hB, Wc, bc, tu, Nn);
    final_out_kernel<<<512, 256, 0, stream>>>(tu, row_ptr, esrc, (float*)d_out, Nn);
}